// Round 1
// baseline (1709.909 us; speedup 1.0000x reference)
//
#include <hip/hip_runtime.h>
#include <stdint.h>

#define DEVFN __device__ __forceinline__

// Fixed problem shape (from reference): x(4,2048,4096) fp32, W(11008,4096) i32,
// snz(32,11008,2) fp32, bias(11008) fp32, GS=128. Out (8192,11008) fp32.
constexpr int M_DIM = 8192;
constexpr int K_DIM = 4096;
constexpr int N_DIM = 11008;
constexpr int GS = 128;
constexpr int NGROUPS = K_DIM / GS;  // 32

typedef __bf16 bf16_t;
typedef bf16_t bf16x8 __attribute__((ext_vector_type(8)));
typedef float f32x4 __attribute__((ext_vector_type(4)));

DEVFN ushort f2bf(float f) {
  uint32_t u = __builtin_bit_cast(uint32_t, f);
  u += 0x7fffu + ((u >> 16) & 1u);   // RNE; inputs are finite
  return (ushort)(u >> 16);
}

// ---------------- x fp32 -> bf16 ----------------
__global__ __launch_bounds__(256) void k_cvt_x(const float* __restrict__ x,
                                               ushort* __restrict__ out) {
  const size_t i4 = (size_t)blockIdx.x * 256 + threadIdx.x;  // quad index, exact grid
  const float4 v = ((const float4*)x)[i4];
  ushort4 r;
  r.x = f2bf(v.x); r.y = f2bf(v.y); r.z = f2bf(v.z); r.w = f2bf(v.w);
  ((ushort4*)out)[i4] = r;
}

// ---------------- W int32 -> bf16 dequant (w*s+z) ----------------
__global__ __launch_bounds__(256) void k_dequant_w(const int* __restrict__ w,
                                                   const float* __restrict__ snz,
                                                   ushort* __restrict__ out) {
  const size_t i4 = (size_t)blockIdx.x * 256 + threadIdx.x;  // quad index, exact grid
  const size_t idx = i4 * 4;
  const int o = (int)(idx >> 12);     // / 4096
  const int i = (int)(idx & 4095);
  const int g = i >> 7;               // / 128 (4 consecutive elems share a group)
  const float2 sz = ((const float2*)snz)[(size_t)g * N_DIM + o];
  const int4 wv = ((const int4*)w)[i4];
  ushort4 r;
  r.x = f2bf((float)wv.x * sz.x + sz.y);
  r.y = f2bf((float)wv.y * sz.x + sz.y);
  r.z = f2bf((float)wv.z * sz.x + sz.y);
  r.w = f2bf((float)wv.w * sz.x + sz.y);
  ((ushort4*)out)[i4] = r;
}

// ---------------- bf16 GEMM (A: MxK, B: NxK i.e. B^T layout), +bias ----------------
constexpr int BM = 128, BN = 128, BK = 32;
constexpr int NBN = N_DIM / BN;      // 86
constexpr int NBM = M_DIM / BM;      // 64
constexpr int KITERS = K_DIM / BK;   // 128

DEVFN void gload_lds16(const ushort* g, ushort* l) {
  __builtin_amdgcn_global_load_lds(
      (const __attribute__((address_space(1))) void*)g,
      (__attribute__((address_space(3))) void*)l,
      16, 0, 0);
}

__global__ __launch_bounds__(256) void k_gemm(const ushort* __restrict__ A,
                                              const ushort* __restrict__ B,
                                              const float* __restrict__ bias,
                                              float* __restrict__ C) {
  // LDS tiles: [row][k], k contiguous (row = 64B). NO padding: global_load_lds
  // writes wave-uniform base + lane*16B, must be contiguous.
  __shared__ __align__(16) ushort As[BM * BK];  // 8 KB
  __shared__ __align__(16) ushort Bs[BN * BK];  // 8 KB

  const int tid = threadIdx.x;
  const int wave = tid >> 6;
  const int lane = tid & 63;

  const int bn = blockIdx.x % NBN;
  const int bm = blockIdx.x / NBN;

  // Staging: tile = 8 KB = 8 chunks of 1024B (16 rows of 64B each).
  // Wave w stages chunks {2w, 2w+1} of A and of B.
  // Within a chunk: lane l -> row 16c + (l>>2), k-bytes (l&3)*16.
  const int c0 = wave * 2;
  const int srow = c0 * 16 + (lane >> 2);
  const int skoff = (lane & 3) * 8;  // in bf16 elems
  const ushort* ag0 = A + (size_t)(bm * BM + srow) * K_DIM + skoff;
  const ushort* ag1 = ag0 + (size_t)16 * K_DIM;
  const ushort* bg0 = B + (size_t)(bn * BN + srow) * K_DIM + skoff;
  const ushort* bg1 = bg0 + (size_t)16 * K_DIM;
  ushort* la0 = &As[c0 * 512];   // 512 ushort = 1024 B
  ushort* la1 = la0 + 512;
  ushort* lb0 = &Bs[c0 * 512];
  ushort* lb1 = lb0 + 512;

  // Compute: wave (wm,wn) owns a 64x64 quadrant; 4x4 tiles of 16x16x32 MFMA.
  // A/B fragment: lane holds elem [lane&15][quad*8 + j] of its 16x32 tile.
  const int wm = (wave & 1) * 64;
  const int wn = (wave >> 1) * 64;
  const int fr = lane & 15;
  const int quad = lane >> 4;
  const ushort* pa = &As[(wm + fr) * BK + quad * 8];
  const ushort* pb = &Bs[(wn + fr) * BK + quad * 8];

  f32x4 acc[4][4] = {};

  for (int kt = 0; kt < KITERS; ++kt) {
    const int k0 = kt * BK;
    gload_lds16(ag0 + k0, la0);
    gload_lds16(ag1 + k0, la1);
    gload_lds16(bg0 + k0, lb0);
    gload_lds16(bg1 + k0, lb1);
    __syncthreads();  // compiler drains vmcnt(0) before s_barrier -> LDS valid

    bf16x8 af[4], bfr[4];
#pragma unroll
    for (int i = 0; i < 4; ++i) {
      af[i]  = *(const bf16x8*)(pa + i * 16 * BK);
      bfr[i] = *(const bf16x8*)(pb + i * 16 * BK);
    }
#pragma unroll
    for (int mi = 0; mi < 4; ++mi)
#pragma unroll
      for (int ni = 0; ni < 4; ++ni)
        acc[mi][ni] = __builtin_amdgcn_mfma_f32_16x16x32_bf16(
            af[mi], bfr[ni], acc[mi][ni], 0, 0, 0);
    __syncthreads();  // protect LDS from next iteration's staging
  }

  // Epilogue. C/D layout (m89/m91 verified): col = lane&15, row = quad*4 + reg.
  const int row0 = bm * BM + wm + quad * 4;
  const int col0 = bn * BN + wn + fr;
#pragma unroll
  for (int ni = 0; ni < 4; ++ni) {
    const int col = col0 + ni * 16;
    const float bv = bias[col];
#pragma unroll
    for (int mi = 0; mi < 4; ++mi) {
      float* cp = C + (size_t)(row0 + mi * 16) * N_DIM + col;
#pragma unroll
      for (int r = 0; r < 4; ++r)
        cp[(size_t)r * N_DIM] = acc[mi][ni][r] + bv;
    }
  }
}

// ---------------- fallback (ws too small): naive but correct ----------------
__global__ __launch_bounds__(256) void k_naive(const float* __restrict__ x,
                                               const int* __restrict__ w,
                                               const float* __restrict__ snz,
                                               const float* __restrict__ bias,
                                               float* __restrict__ y) {
  const int o = blockIdx.x * 256 + threadIdx.x;  // 11008 = 43*256 exact
  const int m = blockIdx.y;
  const float* xr = x + (size_t)m * K_DIM;
  const int* wr = w + (size_t)o * K_DIM;
  float acc = 0.f;
  for (int g = 0; g < NGROUPS; ++g) {
    const float2 sz = ((const float2*)snz)[(size_t)g * N_DIM + o];
    float pd = 0.f, px = 0.f;
    const int base = g * GS;
    for (int i = 0; i < GS; i += 4) {
      float4 xv = *(const float4*)(xr + base + i);
      int4 wv = *(const int4*)(wr + base + i);
      pd += xv.x * wv.x + xv.y * wv.y + xv.z * wv.z + xv.w * wv.w;
      px += xv.x + xv.y + xv.z + xv.w;
    }
    acc += sz.x * pd + sz.y * px;
  }
  y[(size_t)m * N_DIM + o] = acc + bias[o];
}

extern "C" void kernel_launch(void* const* d_in, const int* in_sizes, int n_in,
                              void* d_out, int out_size, void* d_ws, size_t ws_size,
                              hipStream_t stream) {
  const float* x    = (const float*)d_in[0];
  const int*   w    = (const int*)d_in[1];
  const float* snz  = (const float*)d_in[2];
  const float* bias = (const float*)d_in[3];
  float* out = (float*)d_out;

  const size_t wbytes = (size_t)N_DIM * K_DIM * 2;  // 90,177,536
  const size_t xbytes = (size_t)M_DIM * K_DIM * 2;  // 67,108,864

  if (ws_size >= wbytes + xbytes) {
    ushort* wbf = (ushort*)d_ws;
    ushort* xbf = (ushort*)((char*)d_ws + wbytes);
    // x: 8192*4096/4 quads = 8,388,608 -> 32768 blocks exact
    k_cvt_x<<<dim3(32768), dim3(256), 0, stream>>>(x, xbf);
    // W: 11008*4096/4 quads = 11,272,192 -> 44032 blocks exact
    k_dequant_w<<<dim3(44032), dim3(256), 0, stream>>>(w, snz, wbf);
    // GEMM: 64 * 86 = 5504 blocks
    k_gemm<<<dim3(NBM * NBN), dim3(256), 0, stream>>>(xbf, wbf, bias, out);
  } else {
    k_naive<<<dim3(N_DIM / 256, M_DIM), dim3(256), 0, stream>>>(x, w, snz, bias, out);
  }
}

// Round 2
// 1398.223 us; speedup vs baseline: 1.2229x; 1.2229x over previous
//
#include <hip/hip_runtime.h>
#include <stdint.h>

#define DEVFN __device__ __forceinline__

// Fixed problem shape (from reference): x(4,2048,4096) fp32, W(11008,4096) i32,
// snz(32,11008,2) fp32, bias(11008) fp32, GS=128. Out (8192,11008) fp32.
constexpr int M_DIM = 8192;
constexpr int K_DIM = 4096;
constexpr int N_DIM = 11008;
constexpr int GS = 128;
constexpr int NGROUPS = K_DIM / GS;  // 32

typedef __bf16 bf16_t;
typedef bf16_t bf16x8 __attribute__((ext_vector_type(8)));
typedef float f32x4 __attribute__((ext_vector_type(4)));

DEVFN ushort f2bf(float f) {
  uint32_t u = __builtin_bit_cast(uint32_t, f);
  u += 0x7fffu + ((u >> 16) & 1u);   // RNE; inputs are finite
  return (ushort)(u >> 16);
}

// ---------------- x fp32 -> bf16 ----------------
__global__ __launch_bounds__(256) void k_cvt_x(const float* __restrict__ x,
                                               ushort* __restrict__ out) {
  const size_t i4 = (size_t)blockIdx.x * 256 + threadIdx.x;  // quad index, exact grid
  const float4 v = ((const float4*)x)[i4];
  ushort4 r;
  r.x = f2bf(v.x); r.y = f2bf(v.y); r.z = f2bf(v.z); r.w = f2bf(v.w);
  ((ushort4*)out)[i4] = r;
}

// ---------------- W int32 -> bf16 dequant (w*s+z) ----------------
__global__ __launch_bounds__(256) void k_dequant_w(const int* __restrict__ w,
                                                   const float* __restrict__ snz,
                                                   ushort* __restrict__ out) {
  const size_t i4 = (size_t)blockIdx.x * 256 + threadIdx.x;  // quad index, exact grid
  const size_t idx = i4 * 4;
  const int o = (int)(idx >> 12);     // / 4096
  const int i = (int)(idx & 4095);
  const int g = i >> 7;               // / 128 (4 consecutive elems share a group)
  const float2 sz = ((const float2*)snz)[(size_t)g * N_DIM + o];
  const int4 wv = ((const int4*)w)[i4];
  ushort4 r;
  r.x = f2bf((float)wv.x * sz.x + sz.y);
  r.y = f2bf((float)wv.y * sz.x + sz.y);
  r.z = f2bf((float)wv.z * sz.x + sz.y);
  r.w = f2bf((float)wv.w * sz.x + sz.y);
  ((ushort4*)out)[i4] = r;
}

// ---------------- bf16 GEMM (A: MxK, B: NxK i.e. B^T layout), +bias ----------------
constexpr int BM = 128, BN = 128, BK = 32;
constexpr int NBN = N_DIM / BN;      // 86
constexpr int NBM = M_DIM / BM;      // 64
constexpr int KITERS = K_DIM / BK;   // 128

DEVFN void gload_lds16(const ushort* g, ushort* l) {
  __builtin_amdgcn_global_load_lds(
      (const __attribute__((address_space(1))) void*)g,
      (__attribute__((address_space(3))) void*)l,
      16, 0, 0);
}

__global__ __launch_bounds__(256) void k_gemm(const ushort* __restrict__ A,
                                              const ushort* __restrict__ B,
                                              const float* __restrict__ bias,
                                              float* __restrict__ C) {
  // LDS tiles: [row][k], k contiguous (row = 64B). NO padding: global_load_lds
  // writes wave-uniform base + lane*16B, must be contiguous.
  __shared__ __align__(16) ushort As[BM * BK];  // 8 KB
  __shared__ __align__(16) ushort Bs[BN * BK];  // 8 KB

  const int tid = threadIdx.x;
  const int wave = tid >> 6;
  const int lane = tid & 63;

  // XCD-aware swizzle. Dispatch is round-robin across 8 XCDs (bid % 8 = XCD).
  // Each XCD owns an 8-row bm band; within the XCD, blocks go bm-inner so the
  // ~96 co-resident blocks per XCD form an 8(bm) x ~12(bn) rectangle: per
  // K-step footprint (8+12)*8KB = 160 KB << 4 MB L2, so each staged A/B chunk
  // is fetched from L3 once and L2-hit by its other co-resident users.
  // 5504 blocks = 8 xcd * (8 bm_local * 86 bn). Perf-only mapping (G16-safe).
  const int bid = blockIdx.x;
  const int xcd = bid & 7;
  const int local = bid >> 3;          // 0..687
  const int bm = xcd * 8 + (local & 7);
  const int bn = local >> 3;           // 0..85

  // Staging: tile = 8 KB = 8 chunks of 1024B (16 rows of 64B each).
  // Wave w stages chunks {2w, 2w+1} of A and of B.
  // Within a chunk: lane l -> row 16c + (l>>2), k-bytes (l&3)*16.
  const int c0 = wave * 2;
  const int srow = c0 * 16 + (lane >> 2);
  const int skoff = (lane & 3) * 8;  // in bf16 elems
  const ushort* ag0 = A + (size_t)(bm * BM + srow) * K_DIM + skoff;
  const ushort* ag1 = ag0 + (size_t)16 * K_DIM;
  const ushort* bg0 = B + (size_t)(bn * BN + srow) * K_DIM + skoff;
  const ushort* bg1 = bg0 + (size_t)16 * K_DIM;
  ushort* la0 = &As[c0 * 512];   // 512 ushort = 1024 B
  ushort* la1 = la0 + 512;
  ushort* lb0 = &Bs[c0 * 512];
  ushort* lb1 = lb0 + 512;

  // Compute: wave (wm,wn) owns a 64x64 quadrant; 4x4 tiles of 16x16x32 MFMA.
  // A/B fragment: lane holds elem [lane&15][quad*8 + j] of its 16x32 tile.
  const int wm = (wave & 1) * 64;
  const int wn = (wave >> 1) * 64;
  const int fr = lane & 15;
  const int quad = lane >> 4;
  const ushort* pa = &As[(wm + fr) * BK + quad * 8];
  const ushort* pb = &Bs[(wn + fr) * BK + quad * 8];

  f32x4 acc[4][4] = {};

  for (int kt = 0; kt < KITERS; ++kt) {
    const int k0 = kt * BK;
    gload_lds16(ag0 + k0, la0);
    gload_lds16(ag1 + k0, la1);
    gload_lds16(bg0 + k0, lb0);
    gload_lds16(bg1 + k0, lb1);
    __syncthreads();  // compiler drains vmcnt(0) before s_barrier -> LDS valid

    bf16x8 af[4], bfr[4];
#pragma unroll
    for (int i = 0; i < 4; ++i) {
      af[i]  = *(const bf16x8*)(pa + i * 16 * BK);
      bfr[i] = *(const bf16x8*)(pb + i * 16 * BK);
    }
#pragma unroll
    for (int mi = 0; mi < 4; ++mi)
#pragma unroll
      for (int ni = 0; ni < 4; ++ni)
        acc[mi][ni] = __builtin_amdgcn_mfma_f32_16x16x32_bf16(
            af[mi], bfr[ni], acc[mi][ni], 0, 0, 0);
    __syncthreads();  // protect LDS from next iteration's staging
  }

  // Epilogue. C/D layout (m89/m91 verified): col = lane&15, row = quad*4 + reg.
  const int row0 = bm * BM + wm + quad * 4;
  const int col0 = bn * BN + wn + fr;
#pragma unroll
  for (int ni = 0; ni < 4; ++ni) {
    const int col = col0 + ni * 16;
    const float bv = bias[col];
#pragma unroll
    for (int mi = 0; mi < 4; ++mi) {
      float* cp = C + (size_t)(row0 + mi * 16) * N_DIM + col;
#pragma unroll
      for (int r = 0; r < 4; ++r)
        cp[(size_t)r * N_DIM] = acc[mi][ni][r] + bv;
    }
  }
}

// ---------------- fallback (ws too small): naive but correct ----------------
__global__ __launch_bounds__(256) void k_naive(const float* __restrict__ x,
                                               const int* __restrict__ w,
                                               const float* __restrict__ snz,
                                               const float* __restrict__ bias,
                                               float* __restrict__ y) {
  const int o = blockIdx.x * 256 + threadIdx.x;  // 11008 = 43*256 exact
  const int m = blockIdx.y;
  const float* xr = x + (size_t)m * K_DIM;
  const int* wr = w + (size_t)o * K_DIM;
  float acc = 0.f;
  for (int g = 0; g < NGROUPS; ++g) {
    const float2 sz = ((const float2*)snz)[(size_t)g * N_DIM + o];
    float pd = 0.f, px = 0.f;
    const int base = g * GS;
    for (int i = 0; i < GS; i += 4) {
      float4 xv = *(const float4*)(xr + base + i);
      int4 wv = *(const int4*)(wr + base + i);
      pd += xv.x * wv.x + xv.y * wv.y + xv.z * wv.z + xv.w * wv.w;
      px += xv.x + xv.y + xv.z + xv.w;
    }
    acc += sz.x * pd + sz.y * px;
  }
  y[(size_t)m * N_DIM + o] = acc + bias[o];
}

extern "C" void kernel_launch(void* const* d_in, const int* in_sizes, int n_in,
                              void* d_out, int out_size, void* d_ws, size_t ws_size,
                              hipStream_t stream) {
  const float* x    = (const float*)d_in[0];
  const int*   w    = (const int*)d_in[1];
  const float* snz  = (const float*)d_in[2];
  const float* bias = (const float*)d_in[3];
  float* out = (float*)d_out;

  const size_t wbytes = (size_t)N_DIM * K_DIM * 2;  // 90,177,536
  const size_t xbytes = (size_t)M_DIM * K_DIM * 2;  // 67,108,864

  if (ws_size >= wbytes + xbytes) {
    ushort* wbf = (ushort*)d_ws;
    ushort* xbf = (ushort*)((char*)d_ws + wbytes);
    // x: 8192*4096/4 quads = 8,388,608 -> 32768 blocks exact
    k_cvt_x<<<dim3(32768), dim3(256), 0, stream>>>(x, xbf);
    // W: 11008*4096/4 quads = 11,272,192 -> 44032 blocks exact
    k_dequant_w<<<dim3(44032), dim3(256), 0, stream>>>(w, snz, wbf);
    // GEMM: 64 * 86 = 5504 blocks
    k_gemm<<<dim3(NBM * NBN), dim3(256), 0, stream>>>(xbf, wbf, bias, out);
  } else {
    k_naive<<<dim3(N_DIM / 256, M_DIM), dim3(256), 0, stream>>>(x, w, snz, bias, out);
  }
}